// Round 25
// baseline (59.451 us; speedup 1.0000x reference)
//
#include <hip/hip_runtime.h>
#include <math.h>

#define NN 4096
#define NPART 8              // XCDs (for fAll slices + colgood block swizzle)
#define NCHK 256             // input chunks = split blocks (1 per CU)
#define GR 16                // cols per group
#define NGRP 256             // col groups
#define SCAP 32              // per-(group,chunk) slot cap (mean 5, P(>32)~1e-16)
#define HS 4096              // group hash slots (~31% load, ~1.2 probes)
#define NW 16                // waves per phase-2 block (1024 threads)

// mysign(|v|) - 0.5 with reference-faithful overflow: e=inf -> NaN
__device__ __forceinline__ float smh(float v) {
    float e = expf(6.0f * fabsf(v));
    return 0.5f * (e - 1.0f) / (e + 1.0f);
}

// Phase 1 (single pass): one block per chunk reads its 1280 records ONCE,
// stashes each into its column-group's LDS stash (256 stashes x 32 slots =
// 128KB, 1 block/CU). Flush to fixed [group][chunk][SCAP] slots with
// plain-stored counts: no global atomics, no zero-init node (fAll/nAll
// zeroing folded in, 256 floats/block).
__global__ __launch_bounds__(512) void split_k(
    const long* __restrict__ edges, const float* __restrict__ weights,
    const float* __restrict__ stat, const long* __restrict__ edges_c,
    const float* __restrict__ grdt, float4* __restrict__ subseg,
    int* __restrict__ scnt, float* __restrict__ fAll, int E, int EC) {
    __shared__ float4 stash[NGRP][SCAP];       // 128 KB
    __shared__ int cnt[NGRP];
    const int tid = threadIdx.x;
    for (int i = tid; i < NGRP; i += 512) cnt[i] = 0;
    if (tid < 256) fAll[blockIdx.x * 256 + tid] = 0.f;  // zero 2*8*NN floats
    __syncthreads();
    const int chunk = blockIdx.x;
    const int total = E + EC;
    const int csz = (total + NCHK - 1) / NCHK;
    const int lo = chunk * csz;
    const int hi = min(lo + csz, total);
    for (int i = lo + tid; i < hi; i += 512) {
        long e; int isC;
        if (i < E) { e = edges[i]; isC = 0; }
        else { e = edges_c[i - E]; isC = 1; }
        int r = (int)e;              // little-endian: x = low 32 bits
        int c = (int)(e >> 32);
        float4 rec;
        rec.x = __int_as_float((c << 13) | (r << 1) | isC);
        if (isC) { rec.y = grdt[i - E]; rec.z = 0.f; }
        else { rec.y = stat[i]; rec.z = weights[i]; }
        rec.w = 0.f;
        int s = c >> 4;                        // global column group
        int pos = atomicAdd(&cnt[s], 1);       // LDS, 256-way spread (~5/ctr)
        if (pos < SCAP) stash[s][pos] = rec;
    }
    __syncthreads();
    // flat parallel flush: consecutive tid -> consecutive slot (coalesced)
    for (int idx = tid; idx < NGRP * SCAP; idx += 512) {
        int s = idx >> 5, i = idx & (SCAP - 1);
        if (i < cnt[s])
            subseg[((size_t)s * NCHK + chunk) * SCAP + i] = stash[s][i];
    }
    for (int s = tid; s < NGRP; s += 512)
        scnt[s * NCHK + chunk] = min(cnt[s], SCAP);
}

// Phase 2: block per 16-col group. Insert records into LDS hash (coalescing
// duplicate cells = reference scatter-add; 4-lane cluster per chunk).
// Sweep A: v = B*(A-1)+A*W, stash v & smh(v), per-column g/nin -> good =
// clip(g/Nin,-1,1) NaN-propagating (Nin baseline 2048, mysign(0)=0.5).
// Sweep B: row contributions (nout += smh, f += 1-|v-good[c]|/2 over v!=0)
// added DIRECTLY into this XCD's fAll/nAll slice via non-returning
// atomicAdd (~1.3K adds/block, L2-owned lines) -- replaces r23's 32KB LDS
// partial + 8K-atomic flush (2M atomics -> 660K, one fewer barrier).
__global__ __launch_bounds__(1024) void colgood_k(
    const float4* __restrict__ subseg, const int* __restrict__ scnt,
    float* __restrict__ good_buf, float* __restrict__ good_out,
    float* __restrict__ fAll, float* __restrict__ nAll) {
    __shared__ int hkey[HS];
    __shared__ float hA[HS], hW[HS], hB[HS];
    __shared__ int s_cnt[NCHK];
    __shared__ float a1[GR][NW + 1], a2[GR][NW + 1];
    __shared__ float good_l[GR];
    const int tid = threadIdx.x;
    const int wv = tid >> 6;
    const int xcd = blockIdx.x & 7;
    const int g = xcd * 32 + (blockIdx.x >> 3);       // XCD-swizzled group
    const int cb = g * GR;
    for (int i = tid; i < HS; i += 1024) {
        hkey[i] = -1; hA[i] = 0.f; hW[i] = 0.f; hB[i] = 0.f;
    }
    if (tid < NCHK) s_cnt[tid] = scnt[g * NCHK + tid];
    if (tid < GR * (NW + 1)) {
        ((float*)a1)[tid] = 0.f;
        ((float*)a2)[tid] = 0.f;
    }
    __syncthreads();
    {   // insert: 4-lane cluster per chunk (256 chunks, mean 5 recs each)
        const int chunk = tid >> 2;            // 0..255
        const int sub = tid & 3;               // 0..3
        const int n = s_cnt[chunk];
        const float4* sp = subseg + ((size_t)g * NCHK + chunk) * SCAP;
        for (int i = sub; i < n; i += 4) {
            float4 rec = sp[i];
            int ct = __float_as_int(rec.x);
            int c = ct >> 13;
            int r = (ct >> 1) & 4095;
            int key = ((c - cb) << 12) | r;
            int slot = (int)(((unsigned)key * 2654435761u) >> 20) & (HS - 1);
            while (true) {
                int prev = atomicCAS(&hkey[slot], -1, key);
                if (prev == -1 || prev == key) break;
                slot = (slot + 1) & (HS - 1);
            }
            if (ct & 1) {
                atomicAdd(&hB[slot], rec.y);
            } else {
                atomicAdd(&hA[slot], rec.y);
                atomicAdd(&hW[slot], rec.z);
            }
        }
    }
    __syncthreads();
    // Sweep A: v + column sums; stash v and smh(v) for sweep B
#pragma unroll
    for (int k = 0; k < HS / 1024; ++k) {      // 4 slots/thread (exclusive)
        int s = k * 1024 + tid;
        int key = hkey[s];
        if (key != -1) {
            float a = hA[s], w = hW[s], b = hB[s];
            float v = b * (a - 1.0f) + a * w;
            float sv = smh(v);
            hA[s] = v; hW[s] = sv;
            if (v != 0.0f) {                   // zero cells: 0 to all sums
                int d = key >> 12;
                atomicAdd(&a1[d][wv], sv);     // nin, NaN propagates
                atomicAdd(&a2[d][wv], v);      // g (column sum)
            }
        }
    }
    __syncthreads();
    if (tid < GR) {
        float nin = 0.f, gsum = 0.f;
        for (int w2 = 0; w2 < NW; ++w2) { nin += a1[tid][w2]; gsum += a2[tid][w2]; }
        float Nin = 2048.0f + nin;
        float gd = 1.0f;
        if (Nin != 0.0f) {
            float x = gsum / Nin;
            gd = x < -1.0f ? -1.0f : (x > 1.0f ? 1.0f : x);  // NaN stays NaN
        }
        good_l[tid] = gd;
        good_buf[cb + tid] = gd;
        good_out[cb + tid] = gd;
    }
    __syncthreads();
    // Sweep B: row contributions straight into the XCD-local accumulators
    // (reference mask V != 0; NaN propagates through the atomic sums)
    {
        float* fx = fAll + (size_t)xcd * NN;
        float* nx = nAll + (size_t)xcd * NN;
#pragma unroll
        for (int k = 0; k < HS / 1024; ++k) {
            int s = k * 1024 + tid;
            int key = hkey[s];
            if (key != -1) {
                float v = hA[s];
                if (v != 0.0f) {
                    int r = key & 4095;
                    atomicAdd(&nx[r], hW[s]);  // nout
                    atomicAdd(&fx[r],
                              1.0f - 0.5f * fabsf(v - good_l[key >> 12]));
                }
            }
        }
    }
}

// Phase 3: fold 8 XCD partials -> fair (16 blocks); last block: targets gsum.
__global__ __launch_bounds__(256) void fair_k(
    const float* __restrict__ fAll, const float* __restrict__ nAll,
    const float* __restrict__ good_buf, const int* __restrict__ targets,
    int T, float* __restrict__ out) {
    if (blockIdx.x < NN / 256) {
        int r = blockIdx.x * 256 + threadIdx.x;
        float F = 0.f, Nn = 0.f;
        for (int x = 0; x < NPART; ++x) {
            F += fAll[(size_t)x * NN + r];
            Nn += nAll[(size_t)x * NN + r];
        }
        float Nout = 2048.0f + Nn;
        float fair = 1.0f;
        if (Nout != 0.0f) {
            float x = F / Nout;
            fair = x < 0.0f ? 0.0f : (x > 1.0f ? 1.0f : x);  // NaN stays NaN
        }
        out[1 + r] = fair;
    } else {
        float s = 0.f;
        for (int i = threadIdx.x; i < T; i += 256) {
            float gt = good_buf[targets[i]];
            s += (gt == gt) ? gt : 0.0f;       // NaN -> 0
        }
        for (int off = 32; off > 0; off >>= 1) s += __shfl_down(s, off, 64);
        __shared__ float lds[4];
        int lane = threadIdx.x & 63, w = threadIdx.x >> 6;
        if (lane == 0) lds[w] = s;
        __syncthreads();
        if (threadIdx.x == 0) out[0] = lds[0] + lds[1] + lds[2] + lds[3];
    }
}

extern "C" void kernel_launch(void* const* d_in, const int* in_sizes, int n_in,
                              void* d_out, int out_size, void* d_ws, size_t ws_size,
                              hipStream_t stream) {
    const long*  edges   = (const long*)d_in[0];
    const float* weights = (const float*)d_in[1];
    const float* stat    = (const float*)d_in[2];
    const long*  edges_c = (const long*)d_in[3];
    const float* grdt    = (const float*)d_in[4];
    const int*   targets = (const int*)d_in[5];
    const int E  = in_sizes[1];
    const int EC = in_sizes[4];
    const int T  = in_sizes[5];
    float* out = (float*)d_out;

    int*    scnt     = (int*)d_ws;                       // NGRP*NCHK
    float*  good_buf = (float*)(scnt + NGRP * NCHK);     // NN
    float*  fAll     = good_buf + NN;                    // NPART*NN
    float*  nAll     = fAll + (size_t)NPART * NN;        // NPART*NN
    float4* subseg   = (float4*)(nAll + (size_t)NPART * NN); // NGRP*NCHK*SCAP

    split_k<<<NCHK, 512, 0, stream>>>(
        edges, weights, stat, edges_c, grdt, subseg, scnt, fAll, E, EC);

    colgood_k<<<NGRP, 1024, 0, stream>>>(subseg, scnt, good_buf,
                                         out + 1 + NN, fAll, nAll);

    fair_k<<<NN / 256 + 1, 256, 0, stream>>>(fAll, nAll, good_buf,
                                             targets, T, out);
}

// Round 26
// 35.659 us; speedup vs baseline: 1.6672x; 1.6672x over previous
//
#include <hip/hip_runtime.h>
#include <math.h>

#define NN 4096
#define NPART 8              // XCDs (for fAll slices + colgood block swizzle)
#define NCHK 256             // input chunks = split blocks (1 per CU)
#define GR 16                // cols per group
#define NGRP 256             // col groups
#define SCAP 32              // per-(group,chunk) slot cap (mean 5, P(>32)~1e-16)
#define HS 4096              // group hash slots (~31% load, ~1.2 probes)
#define NW 16                // waves per phase-2 block (1024 threads)

// mysign(|v|) - 0.5 with reference-faithful overflow: e=inf -> NaN
__device__ __forceinline__ float smh(float v) {
    float e = expf(6.0f * fabsf(v));
    return 0.5f * (e - 1.0f) / (e + 1.0f);
}

// Phase 1 (single pass, no replication): one block per chunk reads its 1280
// records ONCE and stashes each into its column-group's LDS stash (256
// stashes x 32 slots = 128KB, 1 block/CU, 256 blocks = full machine).
// Flush goes to fixed [group][chunk][SCAP] slots with plain-stored counts:
// no global atomics, no zero-init node (fAll/nAll zeroing folded in, 256
// floats/block).
__global__ __launch_bounds__(512) void split_k(
    const long* __restrict__ edges, const float* __restrict__ weights,
    const float* __restrict__ stat, const long* __restrict__ edges_c,
    const float* __restrict__ grdt, float4* __restrict__ subseg,
    int* __restrict__ scnt, float* __restrict__ fAll, int E, int EC) {
    __shared__ float4 stash[NGRP][SCAP];       // 128 KB
    __shared__ int cnt[NGRP];
    const int tid = threadIdx.x;
    for (int i = tid; i < NGRP; i += 512) cnt[i] = 0;
    if (tid < 256) fAll[blockIdx.x * 256 + tid] = 0.f;  // zero 2*8*NN floats
    __syncthreads();
    const int chunk = blockIdx.x;
    const int total = E + EC;
    const int csz = (total + NCHK - 1) / NCHK;
    const int lo = chunk * csz;
    const int hi = min(lo + csz, total);
    for (int i = lo + tid; i < hi; i += 512) {
        long e; int isC;
        if (i < E) { e = edges[i]; isC = 0; }
        else { e = edges_c[i - E]; isC = 1; }
        int r = (int)e;              // little-endian: x = low 32 bits
        int c = (int)(e >> 32);
        float4 rec;
        rec.x = __int_as_float((c << 13) | (r << 1) | isC);
        if (isC) { rec.y = grdt[i - E]; rec.z = 0.f; }
        else { rec.y = stat[i]; rec.z = weights[i]; }
        rec.w = 0.f;
        int s = c >> 4;                        // global column group
        int pos = atomicAdd(&cnt[s], 1);       // LDS, 256-way spread (~5/ctr)
        if (pos < SCAP) stash[s][pos] = rec;
    }
    __syncthreads();
    // flat parallel flush: consecutive tid -> consecutive slot (coalesced)
    for (int idx = tid; idx < NGRP * SCAP; idx += 512) {
        int s = idx >> 5, i = idx & (SCAP - 1);
        if (i < cnt[s])
            subseg[((size_t)s * NCHK + chunk) * SCAP + i] = stash[s][i];
    }
    for (int s = tid; s < NGRP; s += 512)
        scnt[s * NCHK + chunk] = min(cnt[s], SCAP);
}

// Phase 2: block per 16-col group. Insert records into LDS hash (coalescing
// duplicate cells = reference scatter-add; 4-lane cluster per chunk).
// Sweep A: v = B*(A-1)+A*W, stash v & smh(v), per-column g/nin -> good =
// clip(g/Nin,-1,1) NaN-propagating (Nin baseline 2048, mysign(0)=0.5).
// Sweep B: row contributions (nout += smh, f += 1-|v-good[c]|/2 over v!=0)
// into LDS [4096] partials, flushed via NON-RETURNING atomicAdd into this
// XCD's fAll/nAll slice (8 adds/thread, SEQUENTIAL addresses -> coalesced
// lines; r25 proved scattered per-record global atomics write-through at
// ~40B/record and cost 3x).
__global__ __launch_bounds__(1024) void colgood_k(
    const float4* __restrict__ subseg, const int* __restrict__ scnt,
    float* __restrict__ good_buf, float* __restrict__ good_out,
    float* __restrict__ fAll, float* __restrict__ nAll) {
    __shared__ int hkey[HS];
    __shared__ float hA[HS], hW[HS], hB[HS];
    __shared__ float s_f[NN], s_n[NN];
    __shared__ int s_cnt[NCHK];
    __shared__ float a1[GR][NW + 1], a2[GR][NW + 1];
    __shared__ float good_l[GR];
    const int tid = threadIdx.x;
    const int wv = tid >> 6;
    const int xcd = blockIdx.x & 7;
    const int g = xcd * 32 + (blockIdx.x >> 3);       // XCD-swizzled group
    const int cb = g * GR;
    for (int i = tid; i < HS; i += 1024) {
        hkey[i] = -1; hA[i] = 0.f; hW[i] = 0.f; hB[i] = 0.f;
    }
    for (int i = tid; i < NN; i += 1024) { s_f[i] = 0.f; s_n[i] = 0.f; }
    if (tid < NCHK) s_cnt[tid] = scnt[g * NCHK + tid];
    if (tid < GR * (NW + 1)) {
        ((float*)a1)[tid] = 0.f;
        ((float*)a2)[tid] = 0.f;
    }
    __syncthreads();
    {   // insert: 4-lane cluster per chunk (256 chunks, mean 5 recs each)
        const int chunk = tid >> 2;            // 0..255
        const int sub = tid & 3;               // 0..3
        const int n = s_cnt[chunk];
        const float4* sp = subseg + ((size_t)g * NCHK + chunk) * SCAP;
        for (int i = sub; i < n; i += 4) {
            float4 rec = sp[i];
            int ct = __float_as_int(rec.x);
            int c = ct >> 13;
            int r = (ct >> 1) & 4095;
            int key = ((c - cb) << 12) | r;
            int slot = (int)(((unsigned)key * 2654435761u) >> 20) & (HS - 1);
            while (true) {
                int prev = atomicCAS(&hkey[slot], -1, key);
                if (prev == -1 || prev == key) break;
                slot = (slot + 1) & (HS - 1);
            }
            if (ct & 1) {
                atomicAdd(&hB[slot], rec.y);
            } else {
                atomicAdd(&hA[slot], rec.y);
                atomicAdd(&hW[slot], rec.z);
            }
        }
    }
    __syncthreads();
    // Sweep A: v + column sums; stash v and smh(v) for sweep B
#pragma unroll
    for (int k = 0; k < HS / 1024; ++k) {      // 4 slots/thread (exclusive)
        int s = k * 1024 + tid;
        int key = hkey[s];
        if (key != -1) {
            float a = hA[s], w = hW[s], b = hB[s];
            float v = b * (a - 1.0f) + a * w;
            float sv = smh(v);
            hA[s] = v; hW[s] = sv;
            if (v != 0.0f) {                   // zero cells: 0 to all sums
                int d = key >> 12;
                atomicAdd(&a1[d][wv], sv);     // nin, NaN propagates
                atomicAdd(&a2[d][wv], v);      // g (column sum)
            }
        }
    }
    __syncthreads();
    if (tid < GR) {
        float nin = 0.f, gsum = 0.f;
        for (int w2 = 0; w2 < NW; ++w2) { nin += a1[tid][w2]; gsum += a2[tid][w2]; }
        float Nin = 2048.0f + nin;
        float gd = 1.0f;
        if (Nin != 0.0f) {
            float x = gsum / Nin;
            gd = x < -1.0f ? -1.0f : (x > 1.0f ? 1.0f : x);  // NaN stays NaN
        }
        good_l[tid] = gd;
        good_buf[cb + tid] = gd;
        good_out[cb + tid] = gd;
    }
    __syncthreads();
    // Sweep B: row contributions (reference mask V != 0; NaN propagates)
#pragma unroll
    for (int k = 0; k < HS / 1024; ++k) {
        int s = k * 1024 + tid;
        int key = hkey[s];
        if (key != -1) {
            float v = hA[s];
            if (v != 0.0f) {
                int r = key & 4095;
                atomicAdd(&s_n[r], hW[s]);     // nout partial
                atomicAdd(&s_f[r],
                          1.0f - 0.5f * fabsf(v - good_l[key >> 12]));
            }
        }
    }
    __syncthreads();
    // flush into this XCD's accumulator slice: non-returning, L2-owned,
    // sequential addresses (full-line coalescing)
    float* fx = fAll + (size_t)xcd * NN;
    float* nx = nAll + (size_t)xcd * NN;
    for (int i = tid; i < NN; i += 1024) {
        atomicAdd(&fx[i], s_f[i]);
        atomicAdd(&nx[i], s_n[i]);
    }
}

// Phase 3: fold 8 XCD partials -> fair (16 blocks); last block: targets gsum.
__global__ __launch_bounds__(256) void fair_k(
    const float* __restrict__ fAll, const float* __restrict__ nAll,
    const float* __restrict__ good_buf, const int* __restrict__ targets,
    int T, float* __restrict__ out) {
    if (blockIdx.x < NN / 256) {
        int r = blockIdx.x * 256 + threadIdx.x;
        float F = 0.f, Nn = 0.f;
        for (int x = 0; x < NPART; ++x) {
            F += fAll[(size_t)x * NN + r];
            Nn += nAll[(size_t)x * NN + r];
        }
        float Nout = 2048.0f + Nn;
        float fair = 1.0f;
        if (Nout != 0.0f) {
            float x = F / Nout;
            fair = x < 0.0f ? 0.0f : (x > 1.0f ? 1.0f : x);  // NaN stays NaN
        }
        out[1 + r] = fair;
    } else {
        float s = 0.f;
        for (int i = threadIdx.x; i < T; i += 256) {
            float gt = good_buf[targets[i]];
            s += (gt == gt) ? gt : 0.0f;       // NaN -> 0
        }
        for (int off = 32; off > 0; off >>= 1) s += __shfl_down(s, off, 64);
        __shared__ float lds[4];
        int lane = threadIdx.x & 63, w = threadIdx.x >> 6;
        if (lane == 0) lds[w] = s;
        __syncthreads();
        if (threadIdx.x == 0) out[0] = lds[0] + lds[1] + lds[2] + lds[3];
    }
}

extern "C" void kernel_launch(void* const* d_in, const int* in_sizes, int n_in,
                              void* d_out, int out_size, void* d_ws, size_t ws_size,
                              hipStream_t stream) {
    const long*  edges   = (const long*)d_in[0];
    const float* weights = (const float*)d_in[1];
    const float* stat    = (const float*)d_in[2];
    const long*  edges_c = (const long*)d_in[3];
    const float* grdt    = (const float*)d_in[4];
    const int*   targets = (const int*)d_in[5];
    const int E  = in_sizes[1];
    const int EC = in_sizes[4];
    const int T  = in_sizes[5];
    float* out = (float*)d_out;

    int*    scnt     = (int*)d_ws;                       // NGRP*NCHK
    float*  good_buf = (float*)(scnt + NGRP * NCHK);     // NN
    float*  fAll     = good_buf + NN;                    // NPART*NN
    float*  nAll     = fAll + (size_t)NPART * NN;        // NPART*NN
    float4* subseg   = (float4*)(nAll + (size_t)NPART * NN); // NGRP*NCHK*SCAP

    split_k<<<NCHK, 512, 0, stream>>>(
        edges, weights, stat, edges_c, grdt, subseg, scnt, fAll, E, EC);

    colgood_k<<<NGRP, 1024, 0, stream>>>(subseg, scnt, good_buf,
                                         out + 1 + NN, fAll, nAll);

    fair_k<<<NN / 256 + 1, 256, 0, stream>>>(fAll, nAll, good_buf,
                                             targets, T, out);
}